// Round 10
// baseline (1240.798 us; speedup 1.0000x reference)
//
#include <hip/hip_runtime.h>

#define RH 32
#define RT 2048
#define RC 10

typedef __attribute__((ext_vector_type(8))) _Float16 f16x8;
typedef __attribute__((ext_vector_type(4))) float f32x4;

#define MFMA16(a,b,c) __builtin_amdgcn_mfma_f32_16x16x32_f16((a),(b),(c),0,0,0)

// tanh(x) = 1 - 2/(exp(2x)+1); saturates correctly at +/-inf.
__device__ __forceinline__ float fast_tanh(float x) {
    float e = __builtin_amdgcn_exp2f(x * 2.88539008177792681472f);
    return fmaf(-2.0f, __builtin_amdgcn_rcpf(e + 1.0f), 1.0f);
}

// A-frag rows [base,base+16): lane(n,g) holds W[base+n][k], k = 4g+(e&3)+16*(e>>2)
// (layout validated end-to-end in rounds 4, 5, 7, 8, 9)
__device__ __forceinline__ f16x8 load_wfrag16(const float* __restrict__ W,
                                              int base, int n, int g) {
    f16x8 f;
#pragma unroll
    for (int e = 0; e < 8; ++e) {
        int k = 4*g + (e & 3) + 16*(e >> 2);
        f[e] = (_Float16)W[(base + n)*RH + k];   // RNE
    }
    return f;
}

__global__ __launch_bounds__(64) void rnn2_dual_kernel(
    const float* __restrict__ x,
    const float* __restrict__ W_ih0, const float* __restrict__ W_hh0,
    const float* __restrict__ b_ih0, const float* __restrict__ b_hh0,
    const float* __restrict__ W_ih1, const float* __restrict__ W_hh1,
    const float* __restrict__ b_ih1, const float* __restrict__ b_hh1,
    const float* __restrict__ fc_w, const float* __restrict__ fc_b,
    float* __restrict__ out)
{
    __shared__ float h2fin[32][RH];

    const int ln = threadIdx.x;      // single wave per block, TWO batch tiles
    const int n  = ln & 15;          // batch column within each 16-batch tile
    const int g  = ln >> 4;          // row/k 4-group

    // Shared weight tile-fragments (f16) — used by BOTH tiles.
    f16x8 WI0a = load_wfrag16(W_ih0,  0, n, g);
    f16x8 WI0b = load_wfrag16(W_ih0, 16, n, g);
    f16x8 WH0a = load_wfrag16(W_hh0,  0, n, g);
    f16x8 WH0b = load_wfrag16(W_hh0, 16, n, g);
    f16x8 WI1a = load_wfrag16(W_ih1,  0, n, g);
    f16x8 WI1b = load_wfrag16(W_ih1, 16, n, g);
    f16x8 WH1a = load_wfrag16(W_hh1,  0, n, g);
    f16x8 WH1b = load_wfrag16(W_hh1, 16, n, g);

    f32x4 cb1a, cb1b, cb2a, cb2b;    // bias C-frags (rows 4g+i / 16+4g+i)
#pragma unroll
    for (int i = 0; i < 4; ++i) {
        cb1a[i] = b_ih0[4*g + i]      + b_hh0[4*g + i];
        cb1b[i] = b_ih0[16 + 4*g + i] + b_hh0[16 + 4*g + i];
        cb2a[i] = b_ih1[4*g + i]      + b_hh1[4*g + i];
        cb2b[i] = b_ih1[16 + 4*g + i] + b_hh1[16 + 4*g + i];
    }

    // Per-tile recurrent states (D-frag == next B-frag identity).
    f16x8 h1P, h2P, h1Q, h2Q;
#pragma unroll
    for (int e = 0; e < 8; ++e) {
        h1P[e] = (_Float16)0.0f; h2P[e] = (_Float16)0.0f;
        h1Q[e] = (_Float16)0.0f; h2Q[e] = (_Float16)0.0f;
    }

    // x streams: tile P = batches [32b, 32b+16), tile Q = [32b+16, 32b+32).
    const float* xpP = x + (size_t)(blockIdx.x*32 + n)      * (RT*RH) + 4*g;
    const float* xpQ = x + (size_t)(blockIdx.x*32 + 16 + n) * (RT*RH) + 4*g;

    // 2-slot register rings per tile.
    float4 PA0, PB0, PA1, PB1;       // tile P slots 0,1
    float4 QA0, QB0, QA1, QB1;       // tile Q slots 0,1

#define PREF(A_, B_, XP_, T_) do { \
    const float* p_ = (XP_) + (size_t)(T_) * RH; \
    A_ = *(const float4*)p_; \
    B_ = *(const float4*)(p_ + 16); \
} while (0)

#define CVTX(dst_, A_, B_) do { \
    auto q0_ = __builtin_amdgcn_cvt_pkrtz(A_.x, A_.y); \
    auto q1_ = __builtin_amdgcn_cvt_pkrtz(A_.z, A_.w); \
    auto q2_ = __builtin_amdgcn_cvt_pkrtz(B_.x, B_.y); \
    auto q3_ = __builtin_amdgcn_cvt_pkrtz(B_.z, B_.w); \
    dst_[0] = q0_[0]; dst_[1] = q0_[1]; dst_[2] = q1_[0]; dst_[3] = q1_[1]; \
    dst_[4] = q2_[0]; dst_[5] = q2_[1]; dst_[6] = q3_[0]; dst_[7] = q3_[1]; \
} while (0)

    // One staggered step for one tile (identical arithmetic to round 7):
    // L1 makes h1(t) from pre-update H1_; L2 makes h2(t-1) from the SAME
    // pre-update H1_ and H2_.
#define STEPT(H1_, H2_, XA_, XB_, XP_, T_, DOPREF_) do { \
    f16x8 xf_; CVTX(xf_, XA_, XB_); \
    f32x4 e0_ = MFMA16(WI1a, H1_, cb2a); \
    f32x4 e1_ = MFMA16(WI1b, H1_, cb2b); \
    f32x4 d0_ = MFMA16(WI0a, xf_, cb1a); \
    f32x4 d1_ = MFMA16(WI0b, xf_, cb1b); \
    e0_ = MFMA16(WH1a, H2_, e0_); \
    e1_ = MFMA16(WH1b, H2_, e1_); \
    d0_ = MFMA16(WH0a, H1_, d0_); \
    d1_ = MFMA16(WH0b, H1_, d1_); \
    if (DOPREF_) { PREF(XA_, XB_, XP_, (T_) + 2); } \
    _Pragma("unroll") \
    for (int i_ = 0; i_ < 4; ++i_) { e0_[i_] = fast_tanh(e0_[i_]); e1_[i_] = fast_tanh(e1_[i_]); } \
    _Pragma("unroll") \
    for (int i_ = 0; i_ < 4; ++i_) { H2_[i_] = (_Float16)e0_[i_]; H2_[4+i_] = (_Float16)e1_[i_]; } \
    _Pragma("unroll") \
    for (int i_ = 0; i_ < 4; ++i_) { d0_[i_] = fast_tanh(d0_[i_]); d1_[i_] = fast_tanh(d1_[i_]); } \
    _Pragma("unroll") \
    for (int i_ = 0; i_ < 4; ++i_) { H1_[i_] = (_Float16)d0_[i_]; H1_[4+i_] = (_Float16)d1_[i_]; } \
} while (0)

    // Pair step: both tiles, independent register streams (compiler interleaves).
#define STEP2(SA_, SB_, QA_, QB_, T_, DOPREF_) do { \
    STEPT(h1P, h2P, SA_, SB_, xpP, T_, DOPREF_); \
    STEPT(h1Q, h2Q, QA_, QB_, xpQ, T_, DOPREF_); \
} while (0)

    // Layer-1-only prologue for one tile (h-term exactly zero, skipped).
#define PRO1(H1_, XA_, XB_) do { \
    f16x8 xf_; CVTX(xf_, XA_, XB_); \
    f32x4 d0_ = MFMA16(WI0a, xf_, cb1a); \
    f32x4 d1_ = MFMA16(WI0b, xf_, cb1b); \
    _Pragma("unroll") \
    for (int i_ = 0; i_ < 4; ++i_) { d0_[i_] = fast_tanh(d0_[i_]); d1_[i_] = fast_tanh(d1_[i_]); } \
    _Pragma("unroll") \
    for (int i_ = 0; i_ < 4; ++i_) { H1_[i_] = (_Float16)d0_[i_]; H1_[4+i_] = (_Float16)d1_[i_]; } \
} while (0)

    // Final layer-2-only step for one tile: h2(2047) -> LDS row R_.
#define FIN2(H1_, H2_, R_) do { \
    f32x4 e0_ = MFMA16(WI1a, H1_, cb2a); \
    f32x4 e1_ = MFMA16(WI1b, H1_, cb2b); \
    e0_ = MFMA16(WH1a, H2_, e0_); \
    e1_ = MFMA16(WH1b, H2_, e1_); \
    _Pragma("unroll") \
    for (int i_ = 0; i_ < 4; ++i_) { e0_[i_] = fast_tanh(e0_[i_]); e1_[i_] = fast_tanh(e1_[i_]); } \
    _Pragma("unroll") \
    for (int i_ = 0; i_ < 4; ++i_) { \
        h2fin[R_][4*g + i_]      = e0_[i_]; \
        h2fin[R_][16 + 4*g + i_] = e1_[i_]; \
    } \
} while (0)

    // ---- prologue ----
    PREF(PA0, PB0, xpP, 0); PREF(PA1, PB1, xpP, 1);
    PREF(QA0, QB0, xpQ, 0); PREF(QA1, QB1, xpQ, 1);
    PRO1(h1P, PA0, PB0);
    PRO1(h1Q, QA0, QB0);
    PREF(PA0, PB0, xpP, 2);              // slot 0 <- x(2)
    PREF(QA0, QB0, xpQ, 2);

    // ---- main loop: staggered t = 1..2044 (2 steps/iter) ----
    for (int k = 0; k < 1022; ++k) {
        const int t = 2*k + 1;
        STEP2(PA1, PB1, QA1, QB1, t,     1);   // odd t: slot 1, pref t+2
        STEP2(PA0, PB0, QA0, QB0, t + 1, 1);   // even:  slot 0, pref t+3
    }
    // ---- tail: t = 2045 (pref x2047), 2046, 2047 ----
    STEP2(PA1, PB1, QA1, QB1, 2045, 1);
    STEP2(PA0, PB0, QA0, QB0, 2046, 0);
    STEP2(PA1, PB1, QA1, QB1, 2047, 0);

    // ---- final layer-2-only: h2(2047) for both tiles ----
    FIN2(h1P, h2P, n);
    FIN2(h1Q, h2Q, 16 + n);
#undef STEPT
#undef STEP2
#undef PRO1
#undef FIN2
#undef CVTX
#undef PREF

    __syncthreads();

    // FC epilogue: 32 batches x 10 classes = 320 outputs, 5 per lane.
    for (int c = ln; c < 32 * RC; c += 64) {
        const int bt = c / RC;
        const int cl = c % RC;
        float s = fc_b[cl];
#pragma unroll
        for (int kk = 0; kk < RH; ++kk)
            s = fmaf(fc_w[cl*RH + kk], h2fin[bt][kk], s);
        out[(size_t)(blockIdx.x*32 + bt) * RC + cl] = s;
    }
}

extern "C" void kernel_launch(void* const* d_in, const int* in_sizes, int n_in,
                              void* d_out, int out_size, void* d_ws, size_t ws_size,
                              hipStream_t stream) {
    const float* x     = (const float*)d_in[0];
    const float* W_ih0 = (const float*)d_in[1];
    const float* W_hh0 = (const float*)d_in[2];
    const float* b_ih0 = (const float*)d_in[3];
    const float* b_hh0 = (const float*)d_in[4];
    const float* W_ih1 = (const float*)d_in[5];
    const float* W_hh1 = (const float*)d_in[6];
    const float* b_ih1 = (const float*)d_in[7];
    const float* b_hh1 = (const float*)d_in[8];
    const float* fc_w  = (const float*)d_in[9];
    const float* fc_b  = (const float*)d_in[10];
    float* out = (float*)d_out;

    rnn2_dual_kernel<<<16, 64, 0, stream>>>(x, W_ih0, W_hh0, b_ih0, b_hh0,
                                            W_ih1, W_hh1, b_ih1, b_hh1,
                                            fc_w, fc_b, out);
}